// Round 25
// baseline (66.435 us; speedup 1.0000x reference)
//
#include <hip/hip_runtime.h>
#include <hip/hip_bf16.h>
#include <stdint.h>

// Problem constants
#define B_  64
#define C_  3
#define H_  512
#define W_  512
#define OC_ 16
#define OH_ 510
#define OW_ 510

// R24 with __launch_bounds__(128, 5): VGPR cap ~102 -> 5 waves/SIMD target.
// Single-variable occupancy sweep (4 -> 5); code otherwise identical.
// Verified math unchanged: 32x32x16 MFMA, M-rows (v,oc)-permuted
// (v=(r>>2)&1, oc=(r&3)|((r>>3)<<2)) -> pure in-lane channel-min;
// wave-private 3ch x 6-row LDS ring (slot = row mod 6); 64px x 32row strip.
#define TILES_X_ 8
#define PXW_     68                       // u32 pair slots per line
#define LPW_     (C_ * 6 * PXW_)          // wave-private ring (18 lines)
#define NBLK_    4096                     // 16 blocks/CU, 2 waves/block

typedef __attribute__((ext_vector_type(8)))  short bf16x8;   // MFMA A/B frag
typedef __attribute__((ext_vector_type(16))) float f32x16;   // MFMA C/D frag

// NaN-safe tanh: 1 - 2/(e^{2x}+1); e=inf -> 1 (no inf/inf NaN).
__device__ __forceinline__ float fast_tanh(float v) {
    float e = __expf(2.0f * v);
    return 1.0f - 2.0f * __builtin_amdgcn_rcpf(e + 1.0f);
}
__device__ __forceinline__ uint16_t bf16u(float f) {
    __hip_bfloat16 h = __float2bfloat16(f);   // RNE
    return __builtin_bit_cast(uint16_t, h);
}
__device__ __forceinline__ uint32_t pack2bf(float v0, float v1) {
    return (uint32_t)bf16u(v0) | ((uint32_t)bf16u(v1) << 16);
}
__device__ __forceinline__ float4 ld_f4(const float* p) {
    float4 v;
    __builtin_memcpy(&v, p, 16);   // global_load_dwordx4
    return v;
}

// ---- prep kernel (R19-verified): A-frags (3 ch, permuted rows) + bias ----
// ws: [0) A u16[3][64][8] (3072 B); [3072) bias f32[64][16] (4096 B)
__global__ void conv_prep(const float* __restrict__ wgt,
                          const float* __restrict__ bias,
                          uint16_t* __restrict__ ws16) {
    const int lane = threadIdx.x;        // 0..63
    const int mr = lane & 31;
    const int v  = (mr >> 2) & 1;
    const int oc = (mr & 3) | ((mr >> 3) << 2);
    const int kc = lane >> 5;
    #pragma unroll
    for (int c = 0; c < C_; ++c)
        #pragma unroll
        for (int e = 0; e < 8; ++e) {
            int k  = 8 * kc + e, p = k >> 1, h = k & 1;
            int wr = p >> 1, pk = p & 1;
            int kx = pk ? (h ? -1 : 2) : h;
            int ky = wr - v;
            float w = 0.0f;
            if (kx >= 0 && ky >= 0 && ky <= 2)
                w = wgt[oc * 27 + c * 9 + ky * 3 + kx];
            ws16[(c * 64 + lane) * 8 + e] = bf16u(w);
        }
    float* bp_ = (float*)(ws16 + 1536);  // byte offset 3072
    const int hi = lane >> 5;
    #pragma unroll
    for (int reg = 0; reg < 16; ++reg) {
        int row = (reg & 3) + 8 * (reg >> 2) + 4 * hi;
        bp_[lane * 16 + reg] = bias[(row & 3) | ((row >> 3) << 2)];
    }
}

__global__ __launch_bounds__(128, 5)
void conv3x3_min_tanh_mfma(const float* __restrict__ x,
                           const uint4* __restrict__ wsv,
                           float* __restrict__ out) {
    __shared__ uint32_t lds[2 * LPW_];   // 2 x 4896 B

    const int tid  = threadIdx.x;
    const int lane = tid & 63;
    const int wv   = tid >> 6;
    const int pcol = lane & 31;
    const int hi   = lane >> 5;
    uint32_t* px = lds + wv * LPW_;      // wave-private ring

    // baked A-frags + bias C-init (once per wave, L2-hot 7 KB)
    bf16x8 wfA0 = __builtin_bit_cast(bf16x8, wsv[0 * 64 + lane]);
    bf16x8 wfA1 = __builtin_bit_cast(bf16x8, wsv[1 * 64 + lane]);
    bf16x8 wfA2 = __builtin_bit_cast(bf16x8, wsv[2 * 64 + lane]);
    f32x16 biasv;
    __builtin_memcpy(&biasv, &wsv[192 + lane * 4], 64);

    const int wgid = blockIdx.x * 2 + wv;     // 0..8191 == strip id
    const int rr_  = lane >> 4;               // staging row 0..3
    const int ch_  = lane & 15;               // staging chunk 0..15

    const int b   = wgid >> 7;                // 128 strips per batch image
    const int rem = wgid & 127;
    const int bx  = rem & 7;
    const int sy  = rem >> 3;                 // 0..15
    const int ox0 = min(bx * 64, OW_ - 64);   // <= 446
    const int oyw = min(32 * sy, OH_ - 32);   // <= 478; window rows <= 511

    const float* xb = x + (size_t)b * (C_ * H_ * W_);

    // ---- prologue: wave-local window rows 0..5 -> slots 0..5 (18 lines) ----
    #pragma unroll
    for (int pass = 0; pass < 5; ++pass) {
        int i = pass * 64 + lane;
        if (pass < 4 || lane < 32) {     // 288 items
            int line = i >> 4;           // c*6 + r
            int x0   = 4 * (i & 15);
            int c    = (line >= 6) + (line >= 12);
            int r    = line - 6 * c;
            const float* xrow = xb + ((size_t)(c * H_) + (oyw + r)) * W_ + ox0;
            float4 v = ld_f4(xrow + x0);
            float v4 = xrow[x0 + 4];
            uint4 pk;
            pk.x = pack2bf(v.x, v.y);
            pk.y = pack2bf(v.y, v.z);
            pk.z = pack2bf(v.z, v.w);
            pk.w = pack2bf(v.w, v4);
            *reinterpret_cast<uint4*>(&px[line * PXW_ + x0]) = pk;
        }
    }
    if (lane < 36) {                     // extras x=64,65 per line
        int line = lane >> 1;
        int xx   = 64 + (lane & 1);
        int c    = (line >= 6) + (line >= 12);
        int r    = line - 6 * c;
        const float* xrow = xb + ((size_t)(c * H_) + (oyw + r)) * W_;
        float v0 = xrow[ox0 + xx];
        float v1 = xrow[min(ox0 + xx + 1, W_ - 1)];
        px[line * PXW_ + xx] = pack2bf(v0, v1);
    }

    const size_t obase0 = ((size_t)b * OH_ + oyw) * OW_ + ox0 + pcol;

    // hoisted staging pointers: row (oyw + 6 + rr_), advanced 4*W_ per t
    const float* pr0 = xb + ((size_t)(oyw + 6 + rr_)) * W_ + ox0 + 4 * ch_;
    const float* pr1 = pr0 + (size_t)H_ * W_;
    const float* pr2 = pr1 + (size_t)H_ * W_;
    // extras pointer (lanes 0..23): channel ce_, row offset re_
    const int le_ = lane >> 1, ce_ = le_ >> 2, re_ = le_ & 3;
    const int xxe = 64 + (lane & 1);
    const float* pre = xb + ((size_t)(ce_ * H_) + (oyw + 6 + re_)) * W_;
    const int exa = ox0 + xxe;
    const int exb = min(ox0 + xxe + 1, W_ - 1);

    // one group: compile-time gi/xh, runtime slot base u (even, <=4)
#define GROUP(gi, xh, u)                                                       \
    {                                                                          \
        const int j   = pcol + 32 * (xh);                                      \
        const int b00 = (u) * PXW_ + j;                                        \
        const int b01 = b00 + PXW_;                                            \
        const int b10 = b00 + 6 * PXW_, b11 = b01 + 6 * PXW_;                  \
        const int b20 = b10 + 6 * PXW_, b21 = b11 + 6 * PXW_;                  \
        bf16x8 tb0 = __builtin_bit_cast(bf16x8,                                \
            uint4{px[b00], px[b00 + 2], px[b01], px[b01 + 2]});                \
        bf16x8 tb1 = __builtin_bit_cast(bf16x8,                                \
            uint4{px[b10], px[b10 + 2], px[b11], px[b11 + 2]});                \
        bf16x8 tb2 = __builtin_bit_cast(bf16x8,                                \
            uint4{px[b20], px[b20 + 2], px[b21], px[b21 + 2]});                \
        f32x16 acc = __builtin_amdgcn_mfma_f32_32x32x16_bf16(wfA0, tb0, biasv, 0, 0, 0); \
        acc = __builtin_amdgcn_mfma_f32_32x32x16_bf16(wfA1, tb1, acc, 0, 0, 0);\
        acc = __builtin_amdgcn_mfma_f32_32x32x16_bf16(wfA2, tb2, acc, 0, 0, 0);\
        float n0 = fminf(acc[0], acc[1]),   n1 = fminf(acc[2], acc[3]);        \
        float n2 = fminf(acc[4], acc[5]),   n3 = fminf(acc[6], acc[7]);        \
        float n4 = fminf(acc[8], acc[9]),   n5 = fminf(acc[10], acc[11]);      \
        float n6 = fminf(acc[12], acc[13]), n7 = fminf(acc[14], acc[15]);      \
        float mm = fminf(fminf(fminf(n0, n1), fminf(n2, n3)),                  \
                         fminf(fminf(n4, n5), fminf(n6, n7)));                 \
        float t_ = fast_tanh(fast_tanh(mm));                                   \
        out[obase0 + (size_t)(4 * t + 2 * (gi) + hi) * OW_ + 32 * (xh)] = t_;  \
    }

    // ---- 8 subtiles (4 rows each) through the 6-slot ring; unroll 2 ----
    int st = 0;                          // (4t) mod 6: 0,4,2,...
    #pragma unroll 2
    for (int t = 0; t < 8; ++t) {
        // issue next 4 rows' loads (wave-local rows 4t+6..4t+9)
        float4 L0 = {0,0,0,0}, L1 = {0,0,0,0}, L2 = {0,0,0,0};
        float E0 = 0.f, E1 = 0.f, E2 = 0.f, X0 = 0.f, X1 = 0.f;
        if (t < 7) {
            const float* r0_ = pr0 + (size_t)(4 * t) * W_;
            const float* r1_ = pr1 + (size_t)(4 * t) * W_;
            const float* r2_ = pr2 + (size_t)(4 * t) * W_;
            L0 = ld_f4(r0_); E0 = r0_[4];
            L1 = ld_f4(r1_); E1 = r1_[4];
            L2 = ld_f4(r2_); E2 = r2_[4];
            if (lane < 24) {
                const float* xr_ = pre + (size_t)(4 * t) * W_;
                X0 = xr_[exa];
                X1 = xr_[exb];
            }
        }

        // 4 groups fully unrolled; slot bases from loop-carried st
        {
            int u0 = st + 2 * hi;  u0 -= (u0 >= 6) ? 6 : 0;   // gi=0
            int u1 = u0 + 2;       u1 -= (u1 >= 6) ? 6 : 0;   // gi=1
            GROUP(0, 0, u0)
            GROUP(0, 1, u0)
            GROUP(1, 0, u1)
            GROUP(1, 1, u1)
        }

        // retire ring slots with prefetched rows (slot of row 4t+6 == st);
        // per-wave DS is in-order: these writes follow this t's reads.
        if (t < 7) {
            int s_ = st + rr_;
            s_ -= (s_ >= 6) ? 6 : 0;
            uint4 pk;
            pk.x = pack2bf(L0.x, L0.y); pk.y = pack2bf(L0.y, L0.z);
            pk.z = pack2bf(L0.z, L0.w); pk.w = pack2bf(L0.w, E0);
            *reinterpret_cast<uint4*>(&px[(0 * 6 + s_) * PXW_ + 4 * ch_]) = pk;
            pk.x = pack2bf(L1.x, L1.y); pk.y = pack2bf(L1.y, L1.z);
            pk.z = pack2bf(L1.z, L1.w); pk.w = pack2bf(L1.w, E1);
            *reinterpret_cast<uint4*>(&px[(1 * 6 + s_) * PXW_ + 4 * ch_]) = pk;
            pk.x = pack2bf(L2.x, L2.y); pk.y = pack2bf(L2.y, L2.z);
            pk.z = pack2bf(L2.z, L2.w); pk.w = pack2bf(L2.w, E2);
            *reinterpret_cast<uint4*>(&px[(2 * 6 + s_) * PXW_ + 4 * ch_]) = pk;
            if (lane < 24) {
                int se_ = st + re_;
                se_ -= (se_ >= 6) ? 6 : 0;
                px[(ce_ * 6 + se_) * PXW_ + xxe] = pack2bf(X0, X1);
            }
        }

        st += 4;
        st -= (st >= 6) ? 6 : 0;
    }
#undef GROUP
}

extern "C" void kernel_launch(void* const* d_in, const int* in_sizes, int n_in,
                              void* d_out, int out_size, void* d_ws, size_t ws_size,
                              hipStream_t stream) {
    const float* x    = (const float*)d_in[0];
    const float* wgt  = (const float*)d_in[1];
    const float* bias = (const float*)d_in[2];
    float* out = (float*)d_out;

    conv_prep<<<1, 64, 0, stream>>>(wgt, bias, (uint16_t*)d_ws);
    conv3x3_min_tanh_mfma<<<dim3(NBLK_), 128, 0, stream>>>(
        x, (const uint4*)d_ws, out);
}

// Round 26
// 63.835 us; speedup vs baseline: 1.0407x; 1.0407x over previous
//
#include <hip/hip_runtime.h>
#include <hip/hip_bf16.h>
#include <stdint.h>

// Problem constants
#define B_  64
#define C_  3
#define H_  512
#define W_  512
#define OC_ 16
#define OH_ 510
#define OW_ 510

// R24 optimum (128,4) + work removal:
//  - 8-slot power-of-2 LDS ring (slot = row & 7): AND slot math, no mod-6 folds
//  - min3-structured channel-min (clang fuses fmin triples to v_min3_f32)
// Verified math unchanged: 32x32x16 MFMA, M-rows (v,oc)-permuted
// (v=(r>>2)&1, oc=(r&3)|((r>>3)<<2)) -> pure in-lane channel-min;
// wave-private LDS ring; 64px x 32row strip per wave; persistent 4096 blocks.
#define TILES_X_ 8
#define PXW_     68                       // u32 pair slots per line
#define RDEPTH_  8                        // ring rows per channel (power of 2)
#define LPW_     (C_ * RDEPTH_ * PXW_)    // wave-private ring (24 lines)
#define NBLK_    4096                     // 16 blocks/CU, 2 waves/block

typedef __attribute__((ext_vector_type(8)))  short bf16x8;   // MFMA A/B frag
typedef __attribute__((ext_vector_type(16))) float f32x16;   // MFMA C/D frag

// NaN-safe tanh: 1 - 2/(e^{2x}+1); e=inf -> 1 (no inf/inf NaN).
__device__ __forceinline__ float fast_tanh(float v) {
    float e = __expf(2.0f * v);
    return 1.0f - 2.0f * __builtin_amdgcn_rcpf(e + 1.0f);
}
__device__ __forceinline__ uint16_t bf16u(float f) {
    __hip_bfloat16 h = __float2bfloat16(f);   // RNE
    return __builtin_bit_cast(uint16_t, h);
}
__device__ __forceinline__ uint32_t pack2bf(float v0, float v1) {
    return (uint32_t)bf16u(v0) | ((uint32_t)bf16u(v1) << 16);
}
__device__ __forceinline__ float4 ld_f4(const float* p) {
    float4 v;
    __builtin_memcpy(&v, p, 16);   // global_load_dwordx4
    return v;
}
__device__ __forceinline__ float min3f(float a, float b, float c) {
    return fminf(fminf(a, b), c);   // clang fuses to v_min3_f32
}

// ---- prep kernel (R19-verified): A-frags (3 ch, permuted rows) + bias ----
// ws: [0) A u16[3][64][8] (3072 B); [3072) bias f32[64][16] (4096 B)
__global__ void conv_prep(const float* __restrict__ wgt,
                          const float* __restrict__ bias,
                          uint16_t* __restrict__ ws16) {
    const int lane = threadIdx.x;        // 0..63
    const int mr = lane & 31;
    const int v  = (mr >> 2) & 1;
    const int oc = (mr & 3) | ((mr >> 3) << 2);
    const int kc = lane >> 5;
    #pragma unroll
    for (int c = 0; c < C_; ++c)
        #pragma unroll
        for (int e = 0; e < 8; ++e) {
            int k  = 8 * kc + e, p = k >> 1, h = k & 1;
            int wr = p >> 1, pk = p & 1;
            int kx = pk ? (h ? -1 : 2) : h;
            int ky = wr - v;
            float w = 0.0f;
            if (kx >= 0 && ky >= 0 && ky <= 2)
                w = wgt[oc * 27 + c * 9 + ky * 3 + kx];
            ws16[(c * 64 + lane) * 8 + e] = bf16u(w);
        }
    float* bp_ = (float*)(ws16 + 1536);  // byte offset 3072
    const int hi = lane >> 5;
    #pragma unroll
    for (int reg = 0; reg < 16; ++reg) {
        int row = (reg & 3) + 8 * (reg >> 2) + 4 * hi;
        bp_[lane * 16 + reg] = bias[(row & 3) | ((row >> 3) << 2)];
    }
}

__global__ __launch_bounds__(128, 4)
void conv3x3_min_tanh_mfma(const float* __restrict__ x,
                           const uint4* __restrict__ wsv,
                           float* __restrict__ out) {
    __shared__ uint32_t lds[2 * LPW_];   // 2 x 6528 B = 13.1 KB

    const int tid  = threadIdx.x;
    const int lane = tid & 63;
    const int wv   = tid >> 6;
    const int pcol = lane & 31;
    const int hi   = lane >> 5;
    uint32_t* px = lds + wv * LPW_;      // wave-private ring

    // baked A-frags + bias C-init (once per wave, L2-hot 7 KB)
    bf16x8 wfA0 = __builtin_bit_cast(bf16x8, wsv[0 * 64 + lane]);
    bf16x8 wfA1 = __builtin_bit_cast(bf16x8, wsv[1 * 64 + lane]);
    bf16x8 wfA2 = __builtin_bit_cast(bf16x8, wsv[2 * 64 + lane]);
    f32x16 biasv;
    __builtin_memcpy(&biasv, &wsv[192 + lane * 4], 64);

    const int wgid = blockIdx.x * 2 + wv;     // 0..8191 == strip id
    const int rr_  = lane >> 4;               // staging row 0..3
    const int ch_  = lane & 15;               // staging chunk 0..15

    const int b   = wgid >> 7;                // 128 strips per batch image
    const int rem = wgid & 127;
    const int bx  = rem & 7;
    const int sy  = rem >> 3;                 // 0..15
    const int ox0 = min(bx * 64, OW_ - 64);   // <= 446
    const int oyw = min(32 * sy, OH_ - 32);   // <= 478; window rows <= 511

    const float* xb = x + (size_t)b * (C_ * H_ * W_);

    // ---- prologue: window rows 0..5 -> ring slots 0..5 (18 lines) ----
    #pragma unroll
    for (int pass = 0; pass < 5; ++pass) {
        int i = pass * 64 + lane;
        if (pass < 4 || lane < 32) {     // 288 items
            int line = i >> 4;           // c*6 + r  (r = 0..5)
            int x0   = 4 * (i & 15);
            int c    = (line >= 6) + (line >= 12);
            int r    = line - 6 * c;
            const float* xrow = xb + ((size_t)(c * H_) + (oyw + r)) * W_ + ox0;
            float4 v = ld_f4(xrow + x0);
            float v4 = xrow[x0 + 4];
            uint4 pk;
            pk.x = pack2bf(v.x, v.y);
            pk.y = pack2bf(v.y, v.z);
            pk.z = pack2bf(v.z, v.w);
            pk.w = pack2bf(v.w, v4);
            *reinterpret_cast<uint4*>(&px[(c * RDEPTH_ + r) * PXW_ + x0]) = pk;
        }
    }
    if (lane < 36) {                     // extras x=64,65 per line
        int line = lane >> 1;
        int xx   = 64 + (lane & 1);
        int c    = (line >= 6) + (line >= 12);
        int r    = line - 6 * c;
        const float* xrow = xb + ((size_t)(c * H_) + (oyw + r)) * W_;
        float v0 = xrow[ox0 + xx];
        float v1 = xrow[min(ox0 + xx + 1, W_ - 1)];
        px[(c * RDEPTH_ + r) * PXW_ + xx] = pack2bf(v0, v1);
    }

    const size_t obase0 = ((size_t)b * OH_ + oyw) * OW_ + ox0 + pcol;

    // hoisted staging pointers: row (oyw + 6 + rr_), advanced 4*W_ per t
    const float* pr0 = xb + ((size_t)(oyw + 6 + rr_)) * W_ + ox0 + 4 * ch_;
    const float* pr1 = pr0 + (size_t)H_ * W_;
    const float* pr2 = pr1 + (size_t)H_ * W_;
    // extras pointer (lanes 0..23): channel ce_, row offset re_
    const int le_ = lane >> 1, ce_ = le_ >> 2, re_ = le_ & 3;
    const int xxe = 64 + (lane & 1);
    const float* pre = xb + ((size_t)(ce_ * H_) + (oyw + 6 + re_)) * W_;
    const int exa = ox0 + xxe;
    const int exb = min(ox0 + xxe + 1, W_ - 1);

    // one group: compile-time gi/xh, runtime slot base u (even, 0..6)
#define GROUP(gi, xh, u)                                                       \
    {                                                                          \
        const int j   = pcol + 32 * (xh);                                      \
        const int b00 = (u) * PXW_ + j;                                        \
        const int b01 = b00 + PXW_;             /* u odd-successor, no wrap */ \
        const int b10 = b00 + RDEPTH_ * PXW_, b11 = b01 + RDEPTH_ * PXW_;      \
        const int b20 = b10 + RDEPTH_ * PXW_, b21 = b11 + RDEPTH_ * PXW_;      \
        bf16x8 tb0 = __builtin_bit_cast(bf16x8,                                \
            uint4{px[b00], px[b00 + 2], px[b01], px[b01 + 2]});                \
        bf16x8 tb1 = __builtin_bit_cast(bf16x8,                                \
            uint4{px[b10], px[b10 + 2], px[b11], px[b11 + 2]});                \
        bf16x8 tb2 = __builtin_bit_cast(bf16x8,                                \
            uint4{px[b20], px[b20 + 2], px[b21], px[b21 + 2]});                \
        f32x16 acc = __builtin_amdgcn_mfma_f32_32x32x16_bf16(wfA0, tb0, biasv, 0, 0, 0); \
        acc = __builtin_amdgcn_mfma_f32_32x32x16_bf16(wfA1, tb1, acc, 0, 0, 0);\
        acc = __builtin_amdgcn_mfma_f32_32x32x16_bf16(wfA2, tb2, acc, 0, 0, 0);\
        float m0 = min3f(acc[0],  acc[1],  acc[2]);                            \
        float m1 = min3f(acc[3],  acc[4],  acc[5]);                            \
        float m2 = min3f(acc[6],  acc[7],  acc[8]);                            \
        float m3 = min3f(acc[9],  acc[10], acc[11]);                           \
        float m4 = min3f(acc[12], acc[13], acc[14]);                           \
        float mm = fminf(min3f(m0, m1, m2), min3f(m3, m4, acc[15]));           \
        float t_ = fast_tanh(fast_tanh(mm));                                   \
        out[obase0 + (size_t)(4 * t + 2 * (gi) + hi) * OW_ + 32 * (xh)] = t_;  \
    }

    // ---- 8 subtiles (4 rows each) through the 8-slot ring; unroll 2 ----
    #pragma unroll 2
    for (int t = 0; t < 8; ++t) {
        // issue next 4 rows' loads (wave-local rows 4t+6..4t+9)
        float4 L0 = {0,0,0,0}, L1 = {0,0,0,0}, L2 = {0,0,0,0};
        float E0 = 0.f, E1 = 0.f, E2 = 0.f, X0 = 0.f, X1 = 0.f;
        if (t < 7) {
            const float* r0_ = pr0 + (size_t)(4 * t) * W_;
            const float* r1_ = pr1 + (size_t)(4 * t) * W_;
            const float* r2_ = pr2 + (size_t)(4 * t) * W_;
            L0 = ld_f4(r0_); E0 = r0_[4];
            L1 = ld_f4(r1_); E1 = r1_[4];
            L2 = ld_f4(r2_); E2 = r2_[4];
            if (lane < 24) {
                const float* xr_ = pre + (size_t)(4 * t) * W_;
                X0 = xr_[exa];
                X1 = xr_[exb];
            }
        }

        // 4 groups fully unrolled; AND slot math (ring depth 8)
        {
            int u0 = (4 * t + 2 * hi) & 7;      // even
            int u1 = (u0 + 2) & 7;              // even
            GROUP(0, 0, u0)
            GROUP(0, 1, u0)
            GROUP(1, 0, u1)
            GROUP(1, 1, u1)
        }

        // retire ring slots with prefetched rows: slot = (4t+6+row)&7.
        // Per-wave DS is in-order: these writes follow this t's reads.
        if (t < 7) {
            int s_ = (4 * t + 6 + rr_) & 7;
            uint4 pk;
            pk.x = pack2bf(L0.x, L0.y); pk.y = pack2bf(L0.y, L0.z);
            pk.z = pack2bf(L0.z, L0.w); pk.w = pack2bf(L0.w, E0);
            *reinterpret_cast<uint4*>(&px[(0 * RDEPTH_ + s_) * PXW_ + 4 * ch_]) = pk;
            pk.x = pack2bf(L1.x, L1.y); pk.y = pack2bf(L1.y, L1.z);
            pk.z = pack2bf(L1.z, L1.w); pk.w = pack2bf(L1.w, E1);
            *reinterpret_cast<uint4*>(&px[(1 * RDEPTH_ + s_) * PXW_ + 4 * ch_]) = pk;
            pk.x = pack2bf(L2.x, L2.y); pk.y = pack2bf(L2.y, L2.z);
            pk.z = pack2bf(L2.z, L2.w); pk.w = pack2bf(L2.w, E2);
            *reinterpret_cast<uint4*>(&px[(2 * RDEPTH_ + s_) * PXW_ + 4 * ch_]) = pk;
            if (lane < 24) {
                int se_ = (4 * t + 6 + re_) & 7;
                px[(ce_ * RDEPTH_ + se_) * PXW_ + xxe] = pack2bf(X0, X1);
            }
        }
    }
#undef GROUP
}

extern "C" void kernel_launch(void* const* d_in, const int* in_sizes, int n_in,
                              void* d_out, int out_size, void* d_ws, size_t ws_size,
                              hipStream_t stream) {
    const float* x    = (const float*)d_in[0];
    const float* wgt  = (const float*)d_in[1];
    const float* bias = (const float*)d_in[2];
    float* out = (float*)d_out;

    conv_prep<<<1, 64, 0, stream>>>(wgt, bias, (uint16_t*)d_ws);
    conv3x3_min_tanh_mfma<<<dim3(NBLK_), 128, 0, stream>>>(
        x, (const uint4*)d_ws, out);
}

// Round 27
// 63.729 us; speedup vs baseline: 1.0425x; 1.0017x over previous
//
#include <hip/hip_runtime.h>
#include <hip/hip_bf16.h>
#include <stdint.h>

// Problem constants
#define B_  64
#define C_  3
#define H_  512
#define W_  512
#define OC_ 16
#define OH_ 510
#define OW_ 510

// R26 + work removal round 2:
//  - extras path merged into ch_==15 staging lanes (no separate 24-lane
//    branch, no second address chain; edge pairs via ds_write_b64)
//  - t-loop unroll 4 (cross-iteration overlap; (128,4) cap prevents spill)
// Verified math unchanged: 32x32x16 MFMA, M-rows (v,oc)-permuted
// (v=(r>>2)&1, oc=(r&3)|((r>>3)<<2)) -> pure in-lane channel-min;
// wave-private 8-slot LDS ring (slot = row & 7); 64px x 32row strip.
#define TILES_X_ 8
#define PXW_     68                       // u32 pair slots per line
#define RDEPTH_  8                        // ring rows per channel (power of 2)
#define LPW_     (C_ * RDEPTH_ * PXW_)    // wave-private ring (24 lines)
#define NBLK_    4096                     // 2 waves/block, 8192 strips

typedef __attribute__((ext_vector_type(8)))  short bf16x8;   // MFMA A/B frag
typedef __attribute__((ext_vector_type(16))) float f32x16;   // MFMA C/D frag

// NaN-safe tanh: 1 - 2/(e^{2x}+1); e=inf -> 1 (no inf/inf NaN).
__device__ __forceinline__ float fast_tanh(float v) {
    float e = __expf(2.0f * v);
    return 1.0f - 2.0f * __builtin_amdgcn_rcpf(e + 1.0f);
}
__device__ __forceinline__ uint16_t bf16u(float f) {
    __hip_bfloat16 h = __float2bfloat16(f);   // RNE
    return __builtin_bit_cast(uint16_t, h);
}
__device__ __forceinline__ uint32_t pack2bf(float v0, float v1) {
    return (uint32_t)bf16u(v0) | ((uint32_t)bf16u(v1) << 16);
}
__device__ __forceinline__ float4 ld_f4(const float* p) {
    float4 v;
    __builtin_memcpy(&v, p, 16);   // global_load_dwordx4
    return v;
}
__device__ __forceinline__ float min3f(float a, float b, float c) {
    return fminf(fminf(a, b), c);   // clang fuses to v_min3_f32
}

// ---- prep kernel (R19-verified): A-frags (3 ch, permuted rows) + bias ----
// ws: [0) A u16[3][64][8] (3072 B); [3072) bias f32[64][16] (4096 B)
__global__ void conv_prep(const float* __restrict__ wgt,
                          const float* __restrict__ bias,
                          uint16_t* __restrict__ ws16) {
    const int lane = threadIdx.x;        // 0..63
    const int mr = lane & 31;
    const int v  = (mr >> 2) & 1;
    const int oc = (mr & 3) | ((mr >> 3) << 2);
    const int kc = lane >> 5;
    #pragma unroll
    for (int c = 0; c < C_; ++c)
        #pragma unroll
        for (int e = 0; e < 8; ++e) {
            int k  = 8 * kc + e, p = k >> 1, h = k & 1;
            int wr = p >> 1, pk = p & 1;
            int kx = pk ? (h ? -1 : 2) : h;
            int ky = wr - v;
            float w = 0.0f;
            if (kx >= 0 && ky >= 0 && ky <= 2)
                w = wgt[oc * 27 + c * 9 + ky * 3 + kx];
            ws16[(c * 64 + lane) * 8 + e] = bf16u(w);
        }
    float* bp_ = (float*)(ws16 + 1536);  // byte offset 3072
    const int hi = lane >> 5;
    #pragma unroll
    for (int reg = 0; reg < 16; ++reg) {
        int row = (reg & 3) + 8 * (reg >> 2) + 4 * hi;
        bp_[lane * 16 + reg] = bias[(row & 3) | ((row >> 3) << 2)];
    }
}

__global__ __launch_bounds__(128, 4)
void conv3x3_min_tanh_mfma(const float* __restrict__ x,
                           const uint4* __restrict__ wsv,
                           float* __restrict__ out) {
    __shared__ uint32_t lds[2 * LPW_];   // 2 x 6528 B = 13.1 KB

    const int tid  = threadIdx.x;
    const int lane = tid & 63;
    const int wv   = tid >> 6;
    const int pcol = lane & 31;
    const int hi   = lane >> 5;
    uint32_t* px = lds + wv * LPW_;      // wave-private ring

    // baked A-frags + bias C-init (once per wave, L2-hot 7 KB)
    bf16x8 wfA0 = __builtin_bit_cast(bf16x8, wsv[0 * 64 + lane]);
    bf16x8 wfA1 = __builtin_bit_cast(bf16x8, wsv[1 * 64 + lane]);
    bf16x8 wfA2 = __builtin_bit_cast(bf16x8, wsv[2 * 64 + lane]);
    f32x16 biasv;
    __builtin_memcpy(&biasv, &wsv[192 + lane * 4], 64);

    const int wgid = blockIdx.x * 2 + wv;     // 0..8191 == strip id
    const int rr_  = lane >> 4;               // staging row 0..3
    const int ch_  = lane & 15;               // staging chunk 0..15

    const int b   = wgid >> 7;                // 128 strips per batch image
    const int rem = wgid & 127;
    const int bx  = rem & 7;
    const int sy  = rem >> 3;                 // 0..15
    const int ox0 = min(bx * 64, OW_ - 64);   // <= 446
    const int oyw = min(32 * sy, OH_ - 32);   // <= 478; window rows <= 511

    const float* xb = x + (size_t)b * (C_ * H_ * W_);

    // ---- prologue: window rows 0..5 -> ring slots 0..5 (18 lines) ----
    #pragma unroll
    for (int pass = 0; pass < 5; ++pass) {
        int i = pass * 64 + lane;
        if (pass < 4 || lane < 32) {     // 288 items
            int line = i >> 4;           // c*6 + r  (r = 0..5)
            int x0   = 4 * (i & 15);
            int c    = (line >= 6) + (line >= 12);
            int r    = line - 6 * c;
            const float* xrow = xb + ((size_t)(c * H_) + (oyw + r)) * W_ + ox0;
            float4 v = ld_f4(xrow + x0);
            float v4 = xrow[x0 + 4];
            uint4 pk;
            pk.x = pack2bf(v.x, v.y);
            pk.y = pack2bf(v.y, v.z);
            pk.z = pack2bf(v.z, v.w);
            pk.w = pack2bf(v.w, v4);
            *reinterpret_cast<uint4*>(&px[(c * RDEPTH_ + r) * PXW_ + x0]) = pk;
        }
    }
    if (lane < 36) {                     // prologue extras x=64,65 per line
        int line = lane >> 1;
        int xx   = 64 + (lane & 1);
        int c    = (line >= 6) + (line >= 12);
        int r    = line - 6 * c;
        const float* xrow = xb + ((size_t)(c * H_) + (oyw + r)) * W_;
        float v0 = xrow[ox0 + xx];
        float v1 = xrow[min(ox0 + xx + 1, W_ - 1)];
        px[(c * RDEPTH_ + r) * PXW_ + xx] = pack2bf(v0, v1);
    }

    const size_t obase0 = ((size_t)b * OH_ + oyw) * OW_ + ox0 + pcol;

    // hoisted staging pointers: row (oyw + 6 + rr_), advanced 4*W_ per t.
    // ch_==15 lane's base is at col ox0+60; its x=64..66 edge values live at
    // offsets 4,5 and ex6 = min(ox0+66, 511) - ox0 - 60 (uniform; 6 or 5).
    const float* pr0 = xb + ((size_t)(oyw + 6 + rr_)) * W_ + ox0 + 4 * ch_;
    const float* pr1 = pr0 + (size_t)H_ * W_;
    const float* pr2 = pr1 + (size_t)H_ * W_;
    const int ex6 = min(ox0 + 66, W_ - 1) - ox0 - 60;

    // one group: compile-time gi/xh, runtime slot base u (even, 0..6)
#define GROUP(gi, xh, u)                                                       \
    {                                                                          \
        const int j   = pcol + 32 * (xh);                                      \
        const int b00 = (u) * PXW_ + j;                                        \
        const int b01 = b00 + PXW_;             /* odd successor, no wrap */   \
        const int b10 = b00 + RDEPTH_ * PXW_, b11 = b01 + RDEPTH_ * PXW_;      \
        const int b20 = b10 + RDEPTH_ * PXW_, b21 = b11 + RDEPTH_ * PXW_;      \
        bf16x8 tb0 = __builtin_bit_cast(bf16x8,                                \
            uint4{px[b00], px[b00 + 2], px[b01], px[b01 + 2]});                \
        bf16x8 tb1 = __builtin_bit_cast(bf16x8,                                \
            uint4{px[b10], px[b10 + 2], px[b11], px[b11 + 2]});                \
        bf16x8 tb2 = __builtin_bit_cast(bf16x8,                                \
            uint4{px[b20], px[b20 + 2], px[b21], px[b21 + 2]});                \
        f32x16 acc = __builtin_amdgcn_mfma_f32_32x32x16_bf16(wfA0, tb0, biasv, 0, 0, 0); \
        acc = __builtin_amdgcn_mfma_f32_32x32x16_bf16(wfA1, tb1, acc, 0, 0, 0);\
        acc = __builtin_amdgcn_mfma_f32_32x32x16_bf16(wfA2, tb2, acc, 0, 0, 0);\
        float m0 = min3f(acc[0],  acc[1],  acc[2]);                            \
        float m1 = min3f(acc[3],  acc[4],  acc[5]);                            \
        float m2 = min3f(acc[6],  acc[7],  acc[8]);                            \
        float m3 = min3f(acc[9],  acc[10], acc[11]);                           \
        float m4 = min3f(acc[12], acc[13], acc[14]);                           \
        float mm = fminf(min3f(m0, m1, m2), min3f(m3, m4, acc[15]));           \
        float t_ = fast_tanh(fast_tanh(mm));                                   \
        out[obase0 + (size_t)(4 * t + 2 * (gi) + hi) * OW_ + 32 * (xh)] = t_;  \
    }

    // ---- 8 subtiles (4 rows each) through the 8-slot ring; unroll 4 ----
    #pragma unroll 4
    for (int t = 0; t < 8; ++t) {
        // issue next 4 rows' loads (wave-local rows 4t+6..4t+9)
        float4 L0 = {0,0,0,0}, L1 = {0,0,0,0}, L2 = {0,0,0,0};
        float E0 = 0.f, E1 = 0.f, E2 = 0.f;
        float F0 = 0.f, F1 = 0.f, F2 = 0.f, G0 = 0.f, G1 = 0.f, G2 = 0.f;
        if (t < 7) {
            const float* r0_ = pr0 + (size_t)(4 * t) * W_;
            const float* r1_ = pr1 + (size_t)(4 * t) * W_;
            const float* r2_ = pr2 + (size_t)(4 * t) * W_;
            L0 = ld_f4(r0_); E0 = r0_[4];
            L1 = ld_f4(r1_); E1 = r1_[4];
            L2 = ld_f4(r2_); E2 = r2_[4];
            if (ch_ == 15) {             // edge lanes extend their own rows
                F0 = r0_[5]; G0 = r0_[ex6];
                F1 = r1_[5]; G1 = r1_[ex6];
                F2 = r2_[5]; G2 = r2_[ex6];
            }
        }

        // 4 groups fully unrolled; AND slot math (ring depth 8)
        {
            int u0 = (4 * t + 2 * hi) & 7;      // even
            int u1 = (u0 + 2) & 7;              // even
            GROUP(0, 0, u0)
            GROUP(0, 1, u0)
            GROUP(1, 0, u1)
            GROUP(1, 1, u1)
        }

        // retire ring slots with prefetched rows: slot = (4t+6+row)&7.
        // Per-wave DS is in-order: these writes follow this t's reads.
        if (t < 7) {
            int s_ = (4 * t + 6 + rr_) & 7;
            uint4 pk;
            pk.x = pack2bf(L0.x, L0.y); pk.y = pack2bf(L0.y, L0.z);
            pk.z = pack2bf(L0.z, L0.w); pk.w = pack2bf(L0.w, E0);
            *reinterpret_cast<uint4*>(&px[(0 * RDEPTH_ + s_) * PXW_ + 4 * ch_]) = pk;
            pk.x = pack2bf(L1.x, L1.y); pk.y = pack2bf(L1.y, L1.z);
            pk.z = pack2bf(L1.z, L1.w); pk.w = pack2bf(L1.w, E1);
            *reinterpret_cast<uint4*>(&px[(1 * RDEPTH_ + s_) * PXW_ + 4 * ch_]) = pk;
            pk.x = pack2bf(L2.x, L2.y); pk.y = pack2bf(L2.y, L2.z);
            pk.z = pack2bf(L2.z, L2.w); pk.w = pack2bf(L2.w, E2);
            *reinterpret_cast<uint4*>(&px[(2 * RDEPTH_ + s_) * PXW_ + 4 * ch_]) = pk;
            if (ch_ == 15) {             // edge pairs x=64,65 (8B-aligned b64)
                uint2 p2;
                p2.x = pack2bf(E0, F0); p2.y = pack2bf(F0, G0);
                *reinterpret_cast<uint2*>(&px[(0 * RDEPTH_ + s_) * PXW_ + 64]) = p2;
                p2.x = pack2bf(E1, F1); p2.y = pack2bf(F1, G1);
                *reinterpret_cast<uint2*>(&px[(1 * RDEPTH_ + s_) * PXW_ + 64]) = p2;
                p2.x = pack2bf(E2, F2); p2.y = pack2bf(F2, G2);
                *reinterpret_cast<uint2*>(&px[(2 * RDEPTH_ + s_) * PXW_ + 64]) = p2;
            }
        }
    }
#undef GROUP
}

extern "C" void kernel_launch(void* const* d_in, const int* in_sizes, int n_in,
                              void* d_out, int out_size, void* d_ws, size_t ws_size,
                              hipStream_t stream) {
    const float* x    = (const float*)d_in[0];
    const float* wgt  = (const float*)d_in[1];
    const float* bias = (const float*)d_in[2];
    float* out = (float*)d_out;

    conv_prep<<<1, 64, 0, stream>>>(wgt, bias, (uint16_t*)d_ws);
    conv3x3_min_tanh_mfma<<<dim3(NBLK_), 128, 0, stream>>>(
        x, (const uint4*)d_ws, out);
}